// Round 6
// baseline (1177.694 us; speedup 1.0000x reference)
//
#include <hip/hip_runtime.h>

// Problem constants
#define B_     1
#define CIN_   26
#define HIN_   721
#define WIN_   1440
#define K_     9
#define HOUT_  360
#define KH_    9
#define KW_    9
#define COUT_  256
#define WOUT_  720

#define WT     16                 // w-tile per block (720/16 = 45 tiles)
#define XCOLS  (2*WT + 8)         // 40 staged x columns per row
#define CK     (CIN_ * K_)        // 234
#define ACCP   (WT + 1)           // odd pitch -> conflict-free acc writes

__global__ __launch_bounds__(256, 2)
void disco_fused_kernel(const float* __restrict__ x,
                        const float* __restrict__ psi,
                        const float* __restrict__ weight,
                        const int*   __restrict__ hi_base,
                        float* __restrict__ out)
{
    __shared__ float xs[CIN_][KH_][XCOLS];   // 26*9*40*4 = 37440 B
    __shared__ float acc_s[CK * ACCP];       // 234*17*4 = 15912 B
    __shared__ float psi_s[K_][KH_ * KW_];   // 9*81*4  =  2916 B

    const int tile = blockIdx.x;   // 0..44
    const int h    = blockIdx.y;   // 0..359
    const int w0   = tile * WT;
    const int tid  = threadIdx.x;

    const int hib = hi_base[h];    // in [0, 716]

    // ---- stage psi[k, h, :, :] for all 9 k ----
    for (int i = tid; i < K_ * KH_ * KW_; i += 256) {
        const int k = i / (KH_ * KW_);
        const int j = i % (KH_ * KW_);
        psi_s[k][j] = psi[(k * HOUT_ + h) * (KH_ * KW_) + j];
    }

    // ---- stage x tile: 26 ch x 9 rows x 40 cols (wrap + clip) ----
    const int c0 = 2 * w0 - 4;     // in [-4, 1404]
    for (int i = tid; i < CIN_ * KH_ * XCOLS; i += 256) {
        const int col = i % XCOLS;
        const int rem = i / XCOLS;
        const int dh  = rem % KH_;
        const int c   = rem / KH_;
        int r = hib + dh;
        if (r > HIN_ - 1) r = HIN_ - 1;        // hib >= 0, so only upper clip
        int g = c0 + col;
        if (g < 0)      g += WIN_;
        if (g >= WIN_)  g -= WIN_;
        xs[c][dh][col] = x[(c * HIN_ + r) * WIN_ + g];
    }
    __syncthreads();

    // ---- phase 1: acc[ck][w] = sum_{dh,dw} psi[k,h,dh,dw] * xtile ----
    if (tid < CK) {
        const int c = tid / K_;
        const int k = tid % K_;
        float accw[WT];
        #pragma unroll
        for (int w = 0; w < WT; ++w) accw[w] = 0.f;

        for (int dh = 0; dh < KH_; ++dh) {
            // hoist x row (cols 0 .. 2*(WT-1)+8 = 38) into registers
            float xrow[XCOLS - 1];
            #pragma unroll
            for (int i2 = 0; i2 < XCOLS - 1; ++i2) xrow[i2] = xs[c][dh][i2];
            #pragma unroll
            for (int dw = 0; dw < KW_; ++dw) {
                const float p = psi_s[k][dh * KW_ + dw];
                #pragma unroll
                for (int w = 0; w < WT; ++w)
                    accw[w] = fmaf(p, xrow[2 * w + dw], accw[w]);
            }
        }
        #pragma unroll
        for (int w = 0; w < WT; ++w) acc_s[tid * ACCP + w] = accw[w];
    }
    __syncthreads();

    // ---- phase 2: out[o,h,w0+w] = sum_ck weight[o,ck] * acc[ck][w] ----
    const int o = tid;             // 256 threads == COUT
    float wacc[WT];
    #pragma unroll
    for (int w = 0; w < WT; ++w) wacc[w] = 0.f;

    const float* wrow = weight + o * CK;   // 936 B row, 8B-aligned
    for (int ck2 = 0; ck2 < CK / 2; ++ck2) {
        const float2 wv = *reinterpret_cast<const float2*>(wrow + 2 * ck2);
        const float* ap0 = &acc_s[(2 * ck2 + 0) * ACCP];
        const float* ap1 = &acc_s[(2 * ck2 + 1) * ACCP];
        #pragma unroll
        for (int w = 0; w < WT; ++w)
            wacc[w] = fmaf(wv.x, ap0[w], wacc[w]);
        #pragma unroll
        for (int w = 0; w < WT; ++w)
            wacc[w] = fmaf(wv.y, ap1[w], wacc[w]);
    }

    float* op = out + (size_t)(o * HOUT_ + h) * WOUT_ + w0;
    #pragma unroll
    for (int w = 0; w < WT; w += 4) {
        float4 v = make_float4(wacc[w], wacc[w + 1], wacc[w + 2], wacc[w + 3]);
        *reinterpret_cast<float4*>(op + w) = v;
    }
}

extern "C" void kernel_launch(void* const* d_in, const int* in_sizes, int n_in,
                              void* d_out, int out_size, void* d_ws, size_t ws_size,
                              hipStream_t stream)
{
    const float* x       = (const float*)d_in[0];
    const float* psi     = (const float*)d_in[1];
    const float* weight  = (const float*)d_in[2];
    const int*   hi_base = (const int*)d_in[3];
    float* out = (float*)d_out;

    dim3 grid(WOUT_ / WT, HOUT_, 1);   // 45 x 360
    dim3 block(256, 1, 1);
    hipLaunchKernelGGL(disco_fused_kernel, grid, block, 0, stream,
                       x, psi, weight, hi_base, out);
}

// Round 8
// 594.044 us; speedup vs baseline: 1.9825x; 1.9825x over previous
//
#include <hip/hip_runtime.h>

// Problem constants
#define CIN_   26
#define HIN_   721
#define WIN_   1440
#define K_     9
#define HOUT_  360
#define KH_    9
#define KW_    9
#define COUT_  256
#define WOUT_  720

#define WT     16                 // w-tile per block (720/16 = 45 tiles)
#define XCOLS  (2*WT + 8)         // 40 staged x columns per row
#define CK     (CIN_ * K_)        // 234
#define KPAD   256                // K padded for MFMA (8 k-steps of 32)
#define ACCP   264                // u16 pitch: 528B rows -> 16B aligned, 2-way banks (free)
#define NMT    (COUT_ / 16)       // 16 m-tiles
#define NKS    (KPAD / 32)        // 8 k-steps

typedef short bf16x8 __attribute__((ext_vector_type(8)));
typedef float f32x4  __attribute__((ext_vector_type(4)));

// Fragment-ordered bf16 hi/lo weight: [(mt*8+ks)*64 + lane]*8 + j
__device__ unsigned short g_whi[NMT * NKS * 64 * 8];   // 128 KB
__device__ unsigned short g_wlo[NMT * NKS * 64 * 8];   // 128 KB

__device__ __forceinline__ unsigned short f2bf_rne(float f) {
    union { float f; unsigned u; } v; v.f = f;
    unsigned u = v.u;
    unsigned r = (u + 0x7FFFu + ((u >> 16) & 1u)) >> 16;
    return (unsigned short)r;
}
__device__ __forceinline__ float bf2f(unsigned short b) {
    union { unsigned u; float f; } v; v.u = ((unsigned)b) << 16;
    return v.f;
}

// A-operand layout for mfma_f32_16x16x32_bf16: row m = lane&15, k = ks*32 + (lane>>4)*8 + j
__global__ void prep_weight_kernel(const float* __restrict__ weight) {
    const int bid  = blockIdx.x;        // 0..127  (mt*8 + ks)
    const int mt   = bid / NKS;
    const int ks   = bid % NKS;
    const int lane = threadIdx.x;       // 0..63
    const int m    = mt * 16 + (lane & 15);
    const int k0   = ks * 32 + (lane >> 4) * 8;
    const int base = ((mt * NKS + ks) * 64 + lane) * 8;
    #pragma unroll
    for (int j = 0; j < 8; ++j) {
        const int k = k0 + j;
        const float w = (k < CK) ? weight[m * CK + k] : 0.f;
        const unsigned short hi = f2bf_rne(w);
        g_whi[base + j] = hi;
        g_wlo[base + j] = f2bf_rne(w - bf2f(hi));
    }
}

__global__ __launch_bounds__(256, 2)
void disco_fused_kernel(const float* __restrict__ x,
                        const float* __restrict__ psi,
                        const int*   __restrict__ hi_base,
                        float* __restrict__ out)
{
    __shared__ float xs[CIN_][KH_][XCOLS];                    // 37440 B
    __shared__ __align__(16) unsigned short acc_hi[WT][ACCP]; //  8448 B
    __shared__ __align__(16) unsigned short acc_lo[WT][ACCP]; //  8448 B
    __shared__ float psi_s[K_][KH_ * KW_];                    //  2916 B

    const int tile = blockIdx.x;   // 0..44
    const int h    = blockIdx.y;   // 0..359
    const int w0   = tile * WT;
    const int tid  = threadIdx.x;

    const int hib = hi_base[h];    // in [0, 716]

    // ---- stage psi[k, h, :, :] for all 9 k ----
    for (int i = tid; i < K_ * KH_ * KW_; i += 256) {
        const int k = i / (KH_ * KW_);
        const int j = i % (KH_ * KW_);
        psi_s[k][j] = psi[(k * HOUT_ + h) * (KH_ * KW_) + j];
    }

    // ---- stage x tile: 26 ch x 9 rows x 40 cols (wrap + clip) ----
    const int c0 = 2 * w0 - 4;     // in [-4, 1404]
    for (int i = tid; i < CIN_ * KH_ * XCOLS; i += 256) {
        const int col = i % XCOLS;
        const int rem = i / XCOLS;
        const int dh  = rem % KH_;
        const int c   = rem / KH_;
        int r = hib + dh;
        if (r > HIN_ - 1) r = HIN_ - 1;
        int g = c0 + col;
        if (g < 0)      g += WIN_;
        if (g >= WIN_)  g -= WIN_;
        xs[c][dh][col] = x[(c * HIN_ + r) * WIN_ + g];
    }
    __syncthreads();

    // ---- phase 1: acc[ck][w] stencil, emit bf16 hi/lo into [w][k] layout ----
    if (tid < CK) {
        const int c = tid / K_;
        const int k = tid % K_;
        float accw[WT];
        #pragma unroll
        for (int w = 0; w < WT; ++w) accw[w] = 0.f;

        for (int dh = 0; dh < KH_; ++dh) {
            float xrow[XCOLS - 1];
            #pragma unroll
            for (int i2 = 0; i2 < XCOLS - 1; ++i2) xrow[i2] = xs[c][dh][i2];
            #pragma unroll
            for (int dw = 0; dw < KW_; ++dw) {
                const float p = psi_s[k][dh * KW_ + dw];
                #pragma unroll
                for (int w = 0; w < WT; ++w)
                    accw[w] = fmaf(p, xrow[2 * w + dw], accw[w]);
            }
        }
        #pragma unroll
        for (int w = 0; w < WT; ++w) {
            const unsigned short hi = f2bf_rne(accw[w]);
            acc_hi[w][tid] = hi;
            acc_lo[w][tid] = f2bf_rne(accw[w] - bf2f(hi));
        }
    } else {
        // tid 234..255: zero the k-padding so MFMA B-operand never reads garbage
        #pragma unroll
        for (int w = 0; w < WT; ++w) {
            acc_hi[w][tid] = 0;
            acc_lo[w][tid] = 0;
        }
    }
    __syncthreads();

    // ---- phase 2: C[256x16] = W[256xK] * acc[Kx16] via bf16 MFMA (hi/lo split) ----
    const int lane = tid & 63;
    const int wid  = tid >> 6;          // 4 waves, 4 m-tiles each
    const int n    = lane & 15;         // output w within tile
    const int kg   = lane >> 4;         // k-group

    f32x4 C0 = {0.f, 0.f, 0.f, 0.f};
    f32x4 C1 = C0, C2 = C0, C3 = C0;

    for (int ks = 0; ks < NKS; ++ks) {
        const int kof = ks * 32 + kg * 8;             // multiple of 8 -> 16B aligned
        const bf16x8 bhi = *(const bf16x8*)&acc_hi[n][kof];
        const bf16x8 blo = *(const bf16x8*)&acc_lo[n][kof];

        #pragma unroll
        for (int i = 0; i < 4; ++i) {
            const int mt   = wid * 4 + i;
            const int abase = ((mt * NKS + ks) * 64 + lane) * 8;
            const bf16x8 ahi = *(const bf16x8*)&g_whi[abase];
            const bf16x8 alo = *(const bf16x8*)&g_wlo[abase];
            f32x4 acc = (i == 0) ? C0 : (i == 1) ? C1 : (i == 2) ? C2 : C3;
            acc = __builtin_amdgcn_mfma_f32_16x16x32_bf16(ahi, bhi, acc, 0, 0, 0);
            acc = __builtin_amdgcn_mfma_f32_16x16x32_bf16(ahi, blo, acc, 0, 0, 0);
            acc = __builtin_amdgcn_mfma_f32_16x16x32_bf16(alo, bhi, acc, 0, 0, 0);
            if (i == 0) C0 = acc; else if (i == 1) C1 = acc; else if (i == 2) C2 = acc; else C3 = acc;
        }
    }

    // ---- epilogue: D layout col = lane&15, row = (lane>>4)*4 + reg ----
    #pragma unroll
    for (int i = 0; i < 4; ++i) {
        const f32x4 acc = (i == 0) ? C0 : (i == 1) ? C1 : (i == 2) ? C2 : C3;
        const int m0 = (wid * 4 + i) * 16 + kg * 4;
        #pragma unroll
        for (int r = 0; r < 4; ++r) {
            out[(size_t)(m0 + r) * (HOUT_ * WOUT_) + h * WOUT_ + w0 + n] = acc[r];
        }
    }
}

extern "C" void kernel_launch(void* const* d_in, const int* in_sizes, int n_in,
                              void* d_out, int out_size, void* d_ws, size_t ws_size,
                              hipStream_t stream)
{
    const float* x       = (const float*)d_in[0];
    const float* psi     = (const float*)d_in[1];
    const float* weight  = (const float*)d_in[2];
    const int*   hi_base = (const int*)d_in[3];
    float* out = (float*)d_out;

    hipLaunchKernelGGL(prep_weight_kernel, dim3(NMT * NKS), dim3(64), 0, stream, weight);

    dim3 grid(WOUT_ / WT, HOUT_, 1);   // 45 x 360
    dim3 block(256, 1, 1);
    hipLaunchKernelGGL(disco_fused_kernel, grid, block, 0, stream,
                       x, psi, hi_base, out);
}

// Round 9
// 390.533 us; speedup vs baseline: 3.0156x; 1.5211x over previous
//
#include <hip/hip_runtime.h>

// Problem constants
#define CIN_   26
#define HIN_   721
#define WIN_   1440
#define K_     9
#define HOUT_  360
#define KH_    9
#define KW_    9
#define COUT_  256
#define WOUT_  720

#define WT     16                 // w-tile per block (720/16 = 45 tiles)
#define XCOLS  (2*WT + 8)         // 40 staged x columns per row
#define CK     (CIN_ * K_)        // 234
#define KPAD   256                // K padded for MFMA (8 k-steps of 32)
#define ACCP   264                // u16 pitch: 528B rows -> 16B aligned, 2-way banks (free)
#define NMT    (COUT_ / 16)       // 16 m-tiles
#define NKS    (KPAD / 32)        // 8 k-steps
#define NXCD   8
#define HBAND  (HOUT_ / NXCD)     // 45 h-rows per XCD band

typedef short bf16x8 __attribute__((ext_vector_type(8)));
typedef float f32x4  __attribute__((ext_vector_type(4)));

// Fragment-ordered bf16 weight: [(mt*NKS+ks)*64 + lane]*8 + j   (128 KB)
__device__ unsigned short g_whi[NMT * NKS * 64 * 8];

__device__ __forceinline__ unsigned short f2bf_rne(float f) {
    union { float f; unsigned u; } v; v.f = f;
    unsigned u = v.u;
    unsigned r = (u + 0x7FFFu + ((u >> 16) & 1u)) >> 16;
    return (unsigned short)r;
}

// A-operand layout for mfma_f32_16x16x32_bf16: row m = lane&15, k = ks*32 + (lane>>4)*8 + j
__global__ void prep_weight_kernel(const float* __restrict__ weight) {
    const int bid  = blockIdx.x;        // 0..127  (mt*NKS + ks)
    const int mt   = bid / NKS;
    const int ks   = bid % NKS;
    const int lane = threadIdx.x;       // 0..63
    const int m    = mt * 16 + (lane & 15);
    const int k0   = ks * 32 + (lane >> 4) * 8;
    const int base = ((mt * NKS + ks) * 64 + lane) * 8;
    #pragma unroll
    for (int j = 0; j < 8; ++j) {
        const int k = k0 + j;
        const float w = (k < CK) ? weight[m * CK + k] : 0.f;
        g_whi[base + j] = f2bf_rne(w);
    }
}

__global__ __launch_bounds__(256, 3)
void disco_fused_kernel(const float* __restrict__ x,
                        const float* __restrict__ psi,
                        const int*   __restrict__ hi_base,
                        float* __restrict__ out)
{
    __shared__ float xs[CIN_][KH_][XCOLS];                    // 37440 B
    __shared__ __align__(16) unsigned short acc_s[WT][ACCP];  //  8448 B
    __shared__ float psi_s[K_][KH_ * KW_];                    //  2916 B
                                                              // total 48804 B -> 3 blocks/CU

    // XCD-aware swizzle: blocks dispatch round-robin over 8 XCDs by linear id;
    // give each XCD a contiguous 45-row h band, tiles-within-h innermost so the
    // 9 staged x rows stay L2-hot while 45 w-tiles consume them.
    const int b    = blockIdx.x;        // 0..16199
    const int xcd  = b & (NXCD - 1);
    const int j    = b >> 3;            // 0..2024  (= 45 tiles * 45 h)
    const int h    = xcd * HBAND + j / 45;
    const int tile = j % 45;
    const int w0   = tile * WT;
    const int tid  = threadIdx.x;

    const int hib = hi_base[h];    // in [0, 716]

    // ---- stage psi[k, h, :, :] for all 9 k ----
    for (int i = tid; i < K_ * KH_ * KW_; i += 256) {
        const int k = i / (KH_ * KW_);
        const int jj = i % (KH_ * KW_);
        psi_s[k][jj] = psi[(k * HOUT_ + h) * (KH_ * KW_) + jj];
    }

    // ---- stage x tile: 26 ch x 9 rows x 40 cols (wrap + clip) ----
    const int c0 = 2 * w0 - 4;     // in [-4, 1404]
    for (int i = tid; i < CIN_ * KH_ * XCOLS; i += 256) {
        const int col = i % XCOLS;
        const int rem = i / XCOLS;
        const int dh  = rem % KH_;
        const int c   = rem / KH_;
        int r = hib + dh;
        if (r > HIN_ - 1) r = HIN_ - 1;
        int g = c0 + col;
        if (g < 0)      g += WIN_;
        if (g >= WIN_)  g -= WIN_;
        xs[c][dh][col] = x[(c * HIN_ + r) * WIN_ + g];
    }
    __syncthreads();

    // ---- phase 1: acc[ck][w] stencil, emit single bf16 into [w][k] layout ----
    if (tid < CK) {
        const int c = tid / K_;
        const int k = tid % K_;
        float accw[WT];
        #pragma unroll
        for (int w = 0; w < WT; ++w) accw[w] = 0.f;

        for (int dh = 0; dh < KH_; ++dh) {
            float xrow[XCOLS - 1];
            #pragma unroll
            for (int i2 = 0; i2 < XCOLS - 1; ++i2) xrow[i2] = xs[c][dh][i2];
            #pragma unroll
            for (int dw = 0; dw < KW_; ++dw) {
                const float p = psi_s[k][dh * KW_ + dw];
                #pragma unroll
                for (int w = 0; w < WT; ++w)
                    accw[w] = fmaf(p, xrow[2 * w + dw], accw[w]);
            }
        }
        #pragma unroll
        for (int w = 0; w < WT; ++w)
            acc_s[w][tid] = f2bf_rne(accw[w]);
    } else {
        // tid 234..255: zero the k-padding so MFMA B-operand never reads garbage
        #pragma unroll
        for (int w = 0; w < WT; ++w)
            acc_s[w][tid] = 0;
    }
    __syncthreads();

    // ---- phase 2: C[256x16] = W[256xK] * acc[Kx16] via single-bf16 MFMA ----
    const int lane = tid & 63;
    const int wid  = tid >> 6;          // 4 waves, 4 m-tiles each
    const int n    = lane & 15;         // output w within tile
    const int kg   = lane >> 4;         // k-group

    f32x4 C0 = {0.f, 0.f, 0.f, 0.f};
    f32x4 C1 = C0, C2 = C0, C3 = C0;

    for (int ks = 0; ks < NKS; ++ks) {
        const int kof = ks * 32 + kg * 8;             // multiple of 8 -> 16B aligned
        const bf16x8 bhi = *(const bf16x8*)&acc_s[n][kof];

        #pragma unroll
        for (int i = 0; i < 4; ++i) {
            const int mt    = wid * 4 + i;
            const int abase = ((mt * NKS + ks) * 64 + lane) * 8;
            const bf16x8 ahi = *(const bf16x8*)&g_whi[abase];
            f32x4 acc = (i == 0) ? C0 : (i == 1) ? C1 : (i == 2) ? C2 : C3;
            acc = __builtin_amdgcn_mfma_f32_16x16x32_bf16(ahi, bhi, acc, 0, 0, 0);
            if (i == 0) C0 = acc; else if (i == 1) C1 = acc; else if (i == 2) C2 = acc; else C3 = acc;
        }
    }

    // ---- epilogue: D layout col = lane&15, row = (lane>>4)*4 + reg ----
    #pragma unroll
    for (int i = 0; i < 4; ++i) {
        const f32x4 acc = (i == 0) ? C0 : (i == 1) ? C1 : (i == 2) ? C2 : C3;
        const int m0 = (wid * 4 + i) * 16 + kg * 4;
        #pragma unroll
        for (int r = 0; r < 4; ++r) {
            out[(size_t)(m0 + r) * (HOUT_ * WOUT_) + h * WOUT_ + w0 + n] = acc[r];
        }
    }
}

extern "C" void kernel_launch(void* const* d_in, const int* in_sizes, int n_in,
                              void* d_out, int out_size, void* d_ws, size_t ws_size,
                              hipStream_t stream)
{
    const float* x       = (const float*)d_in[0];
    const float* psi     = (const float*)d_in[1];
    const float* weight  = (const float*)d_in[2];
    const int*   hi_base = (const int*)d_in[3];
    float* out = (float*)d_out;

    hipLaunchKernelGGL(prep_weight_kernel, dim3(NMT * NKS), dim3(64), 0, stream, weight);

    dim3 grid(45 * HOUT_, 1, 1);   // 16200, 1-D for XCD swizzle
    dim3 block(256, 1, 1);
    hipLaunchKernelGGL(disco_fused_kernel, grid, block, 0, stream,
                       x, psi, hi_base, out);
}

// Round 12
// 302.564 us; speedup vs baseline: 3.8924x; 1.2907x over previous
//
#include <hip/hip_runtime.h>

// Problem constants
#define CIN_   26
#define HIN_   721
#define WIN_   1440
#define K_     9
#define HOUT_  360
#define KH_    9
#define KW_    9
#define COUT_  256
#define WOUT_  720

#define WT     16                 // w-tile per block (720/16 = 45 tiles)
#define XCOLS  (2*WT + 8)         // 40 staged x columns per row
#define CK     (CIN_ * K_)        // 234  (== CIN_*KH_, rows of xs)
#define KPAD   256                // phase-2 K padded (8 k-steps of 32)
#define ACCP   264                // u16 pitch: 528B rows, 16B aligned
#define NMT    (COUT_ / 16)       // 16 m-tiles
#define NKS    (KPAD / 32)        // 8 k-steps
#define NXCD   8
#define HBAND  (HOUT_ / NXCD)     // 45 h-rows per XCD band

typedef short bf16x8 __attribute__((ext_vector_type(8)));
typedef float f32x4  __attribute__((ext_vector_type(4)));

// Fragment-ordered bf16 weight: [(mt*NKS+ks)*64 + lane]*8 + j   (128 KB)
__device__ unsigned short g_whi[NMT * NKS * 64 * 8];

__device__ __forceinline__ unsigned short f2bf_rne(float f) {
    union { float f; unsigned u; } v; v.f = f;
    unsigned u = v.u;
    unsigned r = (u + 0x7FFFu + ((u >> 16) & 1u)) >> 16;
    return (unsigned short)r;
}

// A-operand layout for mfma_f32_16x16x32_bf16: row m = lane&15, k = ks*32 + (lane>>4)*8 + j
__global__ void prep_weight_kernel(const float* __restrict__ weight) {
    const int bid  = blockIdx.x;        // 0..127  (mt*NKS + ks)
    const int mt   = bid / NKS;
    const int ks   = bid % NKS;
    const int lane = threadIdx.x;       // 0..63
    const int m    = mt * 16 + (lane & 15);
    const int k0   = ks * 32 + (lane >> 4) * 8;
    const int base = ((mt * NKS + ks) * 64 + lane) * 8;
    #pragma unroll
    for (int j = 0; j < 8; ++j) {
        const int k = k0 + j;
        const float w = (k < CK) ? weight[m * CK + k] : 0.f;
        g_whi[base + j] = f2bf_rne(w);
    }
}

// Phase-1 contraction ordering over the 81 (dh,dw) taps, padded to 96:
//   slot s in [0,72):  dh = s>>3, dw = s&7    (adjacent-dw pairs -> b32 reads)
//   slot s in [72,81): dh = s-72, dw = 8      (the dw=8 singles)
//   slot s in [81,96): zero padding
__global__ __launch_bounds__(256, 4)
void disco_fused_kernel(const float* __restrict__ x,
                        const float* __restrict__ psi,
                        const int*   __restrict__ hi_base,
                        float* __restrict__ out)
{
    __shared__ unsigned short xs_bf[CK][XCOLS];               // 234*40*2 = 18720 B
    __shared__ __align__(16) unsigned short acc_s[WT][ACCP];  //  8448 B
    __shared__ float psi_s[K_][KH_ * KW_];                    //  2916 B
                                                              // total 30084 B -> 4+ blocks/CU

    const int b    = blockIdx.x;        // 0..16199
    const int xcd  = b & (NXCD - 1);
    const int jb   = b >> 3;            // 0..2024
    const int h    = xcd * HBAND + jb / 45;
    const int tile = jb % 45;
    const int w0   = tile * WT;
    const int tid  = threadIdx.x;

    const int hib = hi_base[h];         // in [0, 716]

    // ---- zero acc_s k-padding region [224,256) (phase 1 later overwrites 224..233) ----
    #pragma unroll
    for (int t = 0; t < 2; ++t) {
        const int idx = tid + t * 256;  // 0..511
        acc_s[idx >> 5][224 + (idx & 31)] = 0;
    }

    // ---- stage psi[k, h, :, :] (fp32) ----
    for (int i = tid; i < K_ * KH_ * KW_; i += 256) {
        const int k  = i / 81;
        const int jj = i % 81;
        psi_s[k][jj] = psi[(k * HOUT_ + h) * 81 + jj];
    }

    // ---- stage x tile as bf16: 234 rows (c*9+dh) x 40 cols (wrap + clip) ----
    const int c0 = 2 * w0 - 4;          // in [-4, 1404]
    for (int i = tid; i < CK * XCOLS; i += 256) {
        const int col = i % XCOLS;
        const int row = i / XCOLS;      // c*9 + dh
        const int dh  = row % KH_;
        const int c   = row / KH_;
        int r = hib + dh;
        if (r > HIN_ - 1) r = HIN_ - 1;
        int g = c0 + col;
        if (g < 0)      g += WIN_;
        if (g >= WIN_)  g -= WIN_;
        xs_bf[row][col] = f2bf_rne(x[((size_t)c * HIN_ + r) * WIN_ + g]);
    }
    __syncthreads();

    const int lane = tid & 63;
    const int wid  = tid >> 6;          // 4 waves
    const int n    = lane & 15;
    const int kg   = lane >> 4;

    // ---- phase 1: acc[(c,k)][w] via MFMA, psi as A, xs as B ----
    // A fragments: row m = lane&15 (psi k-index), contraction slot s = ks*32 + kg*8 + e
    bf16x8 afrag[3];
    {
        const int m = n;
        #pragma unroll
        for (int ks = 0; ks < 3; ++ks) {
            union { bf16x8 v; unsigned short u[8]; } af;
            #pragma unroll
            for (int e = 0; e < 8; ++e) {
                const int s = ks * 32 + kg * 8 + e;
                float v = 0.f;
                if (m < 9) {
                    if (s < 72)      v = psi_s[m][(s >> 3) * 9 + (s & 7)];
                    else if (s < 81) v = psi_s[m][(s - 72) * 9 + 8];
                }
                af.u[e] = f2bf_rne(v);
            }
            afrag[ks] = af.v;
        }
    }

    const char* xsb = (const char*)&xs_bf[0][0];
    for (int c = wid; c < CIN_; c += 4) {
        const int base = c * (KH_ * XCOLS * 2) + 4 * n;   // byte offset: c*720 + 4n
        f32x4 C = {0.f, 0.f, 0.f, 0.f};
        #pragma unroll
        for (int ks = 0; ks < 3; ++ks) {
            union { bf16x8 v; unsigned d[4]; unsigned short u[8]; } bf;
            if (ks < 2 || kg == 0) {
                // all-pairs: dh = ks*4 + kg (group-uniform), dwords t -> cols (2n+2t, 2n+2t+1)
                const int dh = ks * 4 + kg;
                const char* p = xsb + base + dh * (XCOLS * 2);
                #pragma unroll
                for (int t = 0; t < 4; ++t)
                    bf.d[t] = *(const unsigned*)(p + 4 * t);
            } else if (kg == 1) {
                // singles s = 72..79: dh = e, dw = 8 -> byte = e*80 + 4n + 16
                #pragma unroll
                for (int e = 0; e < 8; ++e)
                    bf.u[e] = *(const unsigned short*)(xsb + base + e * 80 + 16);
            } else if (kg == 2) {
                bf.d[0] = bf.d[1] = bf.d[2] = bf.d[3] = 0;
                bf.u[0] = *(const unsigned short*)(xsb + base + 8 * 80 + 16);  // s=80: dh=8,dw=8
            } else {
                bf.d[0] = bf.d[1] = bf.d[2] = bf.d[3] = 0;
            }
            C = __builtin_amdgcn_mfma_f32_16x16x32_bf16(afrag[ks], bf.v, C, 0, 0, 0);
        }
        // C row m = kg*4 + r (psi k), col n = w  ->  acc_s[n][c*9 + m]
        #pragma unroll
        for (int r = 0; r < 4; ++r) {
            const int m = kg * 4 + r;
            if (m < 9) acc_s[n][c * 9 + m] = f2bf_rne(C[r]);
        }
    }
    __syncthreads();

    // ---- phase 2: C[256x16] = W[256xK] * acc[Kx16] via bf16 MFMA ----
    f32x4 C0 = {0.f, 0.f, 0.f, 0.f};
    f32x4 C1 = C0, C2 = C0, C3 = C0;

    for (int ks = 0; ks < NKS; ++ks) {
        const int kof = ks * 32 + kg * 8;             // multiple of 8 -> 16B aligned
        const bf16x8 bhi = *(const bf16x8*)&acc_s[n][kof];

        #pragma unroll
        for (int i = 0; i < 4; ++i) {
            const int mt    = wid * 4 + i;
            const int abase = ((mt * NKS + ks) * 64 + lane) * 8;
            const bf16x8 ahi = *(const bf16x8*)&g_whi[abase];
            f32x4 acc = (i == 0) ? C0 : (i == 1) ? C1 : (i == 2) ? C2 : C3;
            acc = __builtin_amdgcn_mfma_f32_16x16x32_bf16(ahi, bhi, acc, 0, 0, 0);
            if (i == 0) C0 = acc; else if (i == 1) C1 = acc; else if (i == 2) C2 = acc; else C3 = acc;
        }
    }

    // ---- epilogue: D layout col = lane&15, row = (lane>>4)*4 + reg ----
    #pragma unroll
    for (int i = 0; i < 4; ++i) {
        const f32x4 acc = (i == 0) ? C0 : (i == 1) ? C1 : (i == 2) ? C2 : C3;
        const int m0 = (wid * 4 + i) * 16 + kg * 4;
        #pragma unroll
        for (int r = 0; r < 4; ++r) {
            out[(size_t)(m0 + r) * (HOUT_ * WOUT_) + h * WOUT_ + w0 + n] = acc[r];
        }
    }
}

extern "C" void kernel_launch(void* const* d_in, const int* in_sizes, int n_in,
                              void* d_out, int out_size, void* d_ws, size_t ws_size,
                              hipStream_t stream)
{
    const float* x       = (const float*)d_in[0];
    const float* psi     = (const float*)d_in[1];
    const float* weight  = (const float*)d_in[2];
    const int*   hi_base = (const int*)d_in[3];
    float* out = (float*)d_out;

    hipLaunchKernelGGL(prep_weight_kernel, dim3(NMT * NKS), dim3(64), 0, stream, weight);

    dim3 grid(45 * HOUT_, 1, 1);   // 16200, 1-D for XCD swizzle
    dim3 block(256, 1, 1);
    hipLaunchKernelGGL(disco_fused_kernel, grid, block, 0, stream,
                       x, psi, hi_base, out);
}